// Round 10
// baseline (7643.328 us; speedup 1.0000x reference)
//
#include <hip/hip_runtime.h>

// LSTM char-RNN scan: B=512, SEQ=1024, UNITS=256, NUM_CHARS=128. fp32 in/out.
// Round 9: r8 structure (REG4/LDS2/STREAM2 per wave, proven 5.95 ms, no spill
// — r8 "spill" was a units misread: FETCH was 6.4 MB, not GB) with the phase
// serialization attacked:
//   - parity-buffered A planes -> ONE __syncthreads per step (was 2)
//   - Wxp gather hoisted to step top (tokens prefetched a step ahead) so its
//     L2 latency hides under the MFMA phase
//   - W streams are step-invariant -> steady-state prefetch of (kt+1)&7 keeps
//     one tile in flight across the barrier
//   - LW trimmed to 15 slots (152 KB LDS total with parity planes); wave 7's
//     second LDS tile becomes a 3rd stream (wave-uniform branch)
// Numerics unchanged: W_h bf16 RNE, h = hi/lo bf16 pair (eff. fp32), c/gates
// fp32. absmax 4.8828e-4 in r5-r9.

#define U       256
#define SEQ     1024
#define NC      128
#define GDIM    1024
#define BCR     16         // batch rows per WG
#define THREADS 512        // 8 waves

typedef short bf16x8 __attribute__((ext_vector_type(8)));
typedef float f32x4  __attribute__((ext_vector_type(4)));

#define WP_OFF   0                        // 512 KB packed W_h
#define WXP_OFF  (512*1024)               // 512 KB packed Wx+bias
#define WS_NEED  (1024*1024)

__device__ __forceinline__ float sig_(float x)  { return 1.0f / (1.0f + __expf(-x)); }
__device__ __forceinline__ float tanh_(float x) { return 1.0f - 2.0f / (__expf(2.0f * x) + 1.0f); }
__device__ __forceinline__ unsigned rne16(float f) {
    union { float f; unsigned u; } v; v.f = f;
    return (v.u + 0x7FFFu + ((v.u >> 16) & 1u)) >> 16;
}
__device__ __forceinline__ float u2f(unsigned u) {
    union { unsigned u; float f; } v; v.u = u; return v.f;
}

// ---- pack W_h into MFMA B-frag order (validated rounds 5-9) ----
__global__ __launch_bounds__(256)
void pack_wh(const float* __restrict__ Wh, uint4* __restrict__ Wp) {
    int i    = blockIdx.x * 256 + threadIdx.x;   // [0, 32768)
    int lane = i & 63;
    int kt   = (i >> 6) & 7;
    int nt   = i >> 9;
    int col  = nt * 16 + (lane & 15);
    int k0   = kt * 32 + ((lane >> 4) * 8);
    const float* base = Wh + (size_t)k0 * GDIM + col;
    unsigned p0 = rne16(base[0 * GDIM]) | (rne16(base[1 * GDIM]) << 16);
    unsigned p1 = rne16(base[2 * GDIM]) | (rne16(base[3 * GDIM]) << 16);
    unsigned p2 = rne16(base[4 * GDIM]) | (rne16(base[5 * GDIM]) << 16);
    unsigned p3 = rne16(base[6 * GDIM]) | (rne16(base[7 * GDIM]) << 16);
    Wp[i] = make_uint4(p0, p1, p2, p3);
}

// ---- pack Wx + bias (+forget_bias) into float4 per (x, unit) ----
__global__ __launch_bounds__(256)
void pack_wx(const float* __restrict__ Wx, const float* __restrict__ bias,
             float4* __restrict__ Wxp) {
    int i = blockIdx.x * 256 + threadIdx.x;      // [0, 32768)
    int x = i >> 8, u = i & 255;
    const float* r = Wx + (size_t)x * GDIM;
    Wxp[i] = make_float4(r[u]       + bias[u],
                         r[256 + u] + bias[256 + u],
                         r[512 + u] + bias[512 + u] + 1.0f,   // forget_bias
                         r[768 + u] + bias[768 + u]);
}

__global__ __launch_bounds__(THREADS, 2)
void lstm_reg(const int* __restrict__ tokens,
              const uint4* __restrict__ Wp,     // packed W_h (ws)
              const float4* __restrict__ Wxp,   // packed Wx+b (ws)
              const float* __restrict__ Wd,     // [256,128]
              const float* __restrict__ bd,     // [128]
              float* __restrict__ out)          // [512,128]
{
    __shared__ uint4 LW[15][8][64];      // 120 KB  W in LDS
    __shared__ short AH[2][8][64][8];    // 16 KB   h hi, parity-buffered
    __shared__ short AL[2][8][64][8];    // 16 KB   h lo residual, parity

    const int tid  = threadIdx.x;
    const int wv   = tid >> 6;        // wave 0..7
    const int lane = tid & 63;
    const int m    = lane & 15;
    const int quad = lane >> 4;
    const int r0   = blockIdx.x * BCR;

    // Ownership: blk A = units wv*16+m (gates nt wv,16+wv,32+wv,48+wv);
    //            blk B = units (8+wv)*16+m (nt 8+wv,24+wv,40+wv,56+wv).
    // REG: {wv, 16+wv, 8+wv, 24+wv}.  LDS: {32+wv} all waves, {40+wv} wv<7.
    // STREAM: {48+wv, 56+wv} all, {40+wv} for wv==7 only.
    bf16x8 WR[4][8];                  // 128 VGPRs
    {
        const int ntR[4] = {wv, 16 + wv, 8 + wv, 24 + wv};
        #pragma unroll
        for (int jj = 0; jj < 4; ++jj)
            #pragma unroll
            for (int kt = 0; kt < 8; ++kt) {
                union { uint4 u; bf16x8 v; } c;
                c.u = Wp[((size_t)(ntR[jj] * 8 + kt)) * 64 + lane];
                WR[jj][kt] = c.v;
            }
    }
    const int slA = 2 * wv;                      // 0,2,..,14
    #pragma unroll
    for (int kt = 0; kt < 8; ++kt)
        LW[slA][kt][lane] = Wp[((size_t)((32 + wv) * 8 + kt)) * 64 + lane];
    if (wv < 7) {
        #pragma unroll
        for (int kt = 0; kt < 8; ++kt)
            LW[slA + 1][kt][lane] = Wp[((size_t)((40 + wv) * 8 + kt)) * 64 + lane];
    }
    for (int i = tid; i < 4096; i += THREADS) {  // zero both parities
        ((int*)AH)[i] = 0;
        ((int*)AL)[i] = 0;
    }

    float cst[2][4] = {{0.f, 0.f, 0.f, 0.f}, {0.f, 0.f, 0.f, 0.f}};
    const int uA = wv * 16 + m;
    const int uB = (8 + wv) * 16 + m;
    const uint4* sp0 = Wp + ((size_t)(48 + wv) * 8) * 64 + lane;
    const uint4* sp1 = Wp + ((size_t)(56 + wv) * 8) * 64 + lane;
    const uint4* sp2 = Wp + ((size_t)(40 + wv) * 8) * 64 + lane;   // wv==7

    __syncthreads();

    // token prefetch for t=0; streams primed at kt=0
    int tokc[4];
    #pragma unroll
    for (int ri = 0; ri < 4; ++ri)
        tokc[ri] = tokens[(size_t)(r0 + quad * 4 + ri) * SEQ];
    uint4 s0 = sp0[0], s1 = sp1[0], s2;
    if (wv == 7) s2 = sp2[0];

    for (int t = 0; t < SEQ; ++t) {
        const int p = t & 1;

        // ---- hoisted gathers: Wxp for this step, tokens for next ----
        float4 wxA[4], wxB[4];
        #pragma unroll
        for (int ri = 0; ri < 4; ++ri) {
            wxA[ri] = Wxp[(size_t)tokc[ri] * 256 + uA];
            wxB[ri] = Wxp[(size_t)tokc[ri] * 256 + uB];
        }
        const int tn = (t + 1 < SEQ) ? t + 1 : t;
        int tokn[4];
        #pragma unroll
        for (int ri = 0; ri < 4; ++ri)
            tokn[ri] = tokens[(size_t)(r0 + quad * 4 + ri) * SEQ + tn];

        // ---- MFMA phase ----
        f32x4 acc[8];
        #pragma unroll
        for (int j = 0; j < 8; ++j) acc[j] = (f32x4){0.f, 0.f, 0.f, 0.f};

        #pragma unroll
        for (int kt = 0; kt < 8; ++kt) {
            bf16x8 ah = *(const bf16x8*)&AH[p][kt][lane][0];
            bf16x8 al = *(const bf16x8*)&AL[p][kt][lane][0];
            const int kn = (kt + 1) & 7;          // steady-state stream pipeline
            uint4 n0 = sp0[kn * 64];
            uint4 n1 = sp1[kn * 64];
            uint4 n2;
            if (wv == 7) n2 = sp2[kn * 64];
            union { uint4 u; bf16x8 v; } l0, l1, b0, b1;
            l0.u = LW[slA][kt][lane];
            if (wv < 7) l1.u = LW[slA + 1][kt][lane];
            else        l1.u = s2;
            b0.u = s0; b1.u = s1;
            acc[0] = __builtin_amdgcn_mfma_f32_16x16x32_bf16(ah, WR[0][kt], acc[0], 0, 0, 0);
            acc[0] = __builtin_amdgcn_mfma_f32_16x16x32_bf16(al, WR[0][kt], acc[0], 0, 0, 0);
            acc[1] = __builtin_amdgcn_mfma_f32_16x16x32_bf16(ah, WR[1][kt], acc[1], 0, 0, 0);
            acc[1] = __builtin_amdgcn_mfma_f32_16x16x32_bf16(al, WR[1][kt], acc[1], 0, 0, 0);
            acc[2] = __builtin_amdgcn_mfma_f32_16x16x32_bf16(ah, l0.v, acc[2], 0, 0, 0);
            acc[2] = __builtin_amdgcn_mfma_f32_16x16x32_bf16(al, l0.v, acc[2], 0, 0, 0);
            acc[3] = __builtin_amdgcn_mfma_f32_16x16x32_bf16(ah, b0.v, acc[3], 0, 0, 0);
            acc[3] = __builtin_amdgcn_mfma_f32_16x16x32_bf16(al, b0.v, acc[3], 0, 0, 0);
            acc[4] = __builtin_amdgcn_mfma_f32_16x16x32_bf16(ah, WR[2][kt], acc[4], 0, 0, 0);
            acc[4] = __builtin_amdgcn_mfma_f32_16x16x32_bf16(al, WR[2][kt], acc[4], 0, 0, 0);
            acc[5] = __builtin_amdgcn_mfma_f32_16x16x32_bf16(ah, WR[3][kt], acc[5], 0, 0, 0);
            acc[5] = __builtin_amdgcn_mfma_f32_16x16x32_bf16(al, WR[3][kt], acc[5], 0, 0, 0);
            acc[6] = __builtin_amdgcn_mfma_f32_16x16x32_bf16(ah, l1.v, acc[6], 0, 0, 0);
            acc[6] = __builtin_amdgcn_mfma_f32_16x16x32_bf16(al, l1.v, acc[6], 0, 0, 0);
            acc[7] = __builtin_amdgcn_mfma_f32_16x16x32_bf16(ah, b1.v, acc[7], 0, 0, 0);
            acc[7] = __builtin_amdgcn_mfma_f32_16x16x32_bf16(al, b1.v, acc[7], 0, 0, 0);
            s0 = n0; s1 = n1;
            if (wv == 7) s2 = n2;
        }

        // ---- in-register LSTM update ----
        unsigned hh[2][4], hl[2][4];
        #pragma unroll
        for (int blk = 0; blk < 2; ++blk) {
            #pragma unroll
            for (int ri = 0; ri < 4; ++ri) {
                float4 wx = blk ? wxB[ri] : wxA[ri];
                float gi = acc[blk * 4 + 0][ri] + wx.x;
                float gj = acc[blk * 4 + 1][ri] + wx.y;
                float gf = acc[blk * 4 + 2][ri] + wx.z;   // forget_bias folded
                float go = acc[blk * 4 + 3][ri] + wx.w;
                float c  = cst[blk][ri];
                c = c * sig_(gf) + sig_(gi) * tanh_(gj);
                cst[blk][ri] = c;
                float nh = tanh_(c) * sig_(go);
                unsigned hi = rne16(nh);
                hh[blk][ri] = hi;
                hl[blk][ri] = rne16(nh - u2f(hi << 16));
            }
        }

        // ---- store to opposite parity; single barrier ----
        short* dH = &AH[1 - p][0][0][0];
        short* dL = &AL[1 - p][0][0][0];
        #pragma unroll
        for (int blk = 0; blk < 2; ++blk) {
            const int u = (wv + 8 * blk) * 16 + m;
            const int kt_u = u >> 5, qa = (u >> 3) & 3, ju = u & 7;
            #pragma unroll
            for (int ri = 0; ri < 4; ++ri) {
                const int row = quad * 4 + ri;
                const int idx = ((kt_u * 64 + qa * 16 + row) << 3) + ju;
                dH[idx] = (short)hh[blk][ri];
                dL[idx] = (short)hl[blk][ri];
            }
        }
        __syncthreads();

        #pragma unroll
        for (int ri = 0; ri < 4; ++ri) tokc[ri] = tokn[ri];
    }

    // ---- final dense (h lives in parity plane 0 after t=1023) ----
    for (int o = tid; o < BCR * NC; o += THREADS) {
        const int r = o >> 7;
        const int n = o & (NC - 1);
        float sum = bd[n];
        #pragma unroll 4
        for (int k = 0; k < U; ++k) {
            const int idx = (((k >> 5) * 64 + ((k >> 3) & 3) * 16 + r) << 3) + (k & 7);
            float hk = u2f(((unsigned)(unsigned short)(&AH[0][0][0][0])[idx]) << 16)
                     + u2f(((unsigned)(unsigned short)(&AL[0][0][0][0])[idx]) << 16);
            sum = fmaf(hk, Wd[k * NC + n], sum);
        }
        out[(size_t)(r0 + r) * NC + n] = sum;
    }
}

// ================= fallback: round-5 streaming kernel (proven 7.6 ms) =========
__global__ __launch_bounds__(256)
void pack_kq(const float* __restrict__ Wh, uint4* __restrict__ Whb) {
    int idx = blockIdx.x * 256 + threadIdx.x;
    int kq  = idx >> 10;
    int c   = idx & 1023;
    const float* base = Wh + (size_t)(kq * 8) * GDIM + c;
    unsigned p0 = rne16(base[0 * GDIM]) | (rne16(base[1 * GDIM]) << 16);
    unsigned p1 = rne16(base[2 * GDIM]) | (rne16(base[3 * GDIM]) << 16);
    unsigned p2 = rne16(base[4 * GDIM]) | (rne16(base[5 * GDIM]) << 16);
    unsigned p3 = rne16(base[6 * GDIM]) | (rne16(base[7 * GDIM]) << 16);
    Whb[idx] = make_uint4(p0, p1, p2, p3);
}

__global__ __launch_bounds__(1024, 4)
void lstm_stream(const int* __restrict__ tokens, const float* __restrict__ Wx,
                 const uint4* __restrict__ Whb, const float* __restrict__ bias,
                 const float* __restrict__ Wd, const float* __restrict__ bd,
                 float* __restrict__ out)
{
    __shared__ float h32[2][U];
    __shared__ float G2[GDIM][2];
    __shared__ int   tok[2][SEQ];
    const int tid = threadIdx.x;
    const int r0  = blockIdx.x * 2;
    for (int i = tid; i < 2 * SEQ; i += 1024)
        ((int*)tok)[i] = tokens[r0 * SEQ + i];
    if (tid < 2 * U) ((float*)h32)[tid] = 0.0f;
    const float b_c = bias[tid];
    float c_state = 0.0f;
    const int ur = tid >> 8, uu = tid & 255;
    __syncthreads();
    const uint4* wp = Whb + tid;
    for (int t = 0; t < SEQ; ++t) {
        const int x0 = tok[0][t], x1 = tok[1][t];
        float a0e = Wx[x0 * GDIM + tid] + b_c;
        float a1e = Wx[x1 * GDIM + tid] + b_c;
        float a0o = 0.f, a1o = 0.f;
        #pragma unroll 4
        for (int kq = 0; kq < 32; ++kq) {
            float4 h0a = *(const float4*)&h32[0][kq * 8];
            float4 h0b = *(const float4*)&h32[0][kq * 8 + 4];
            float4 h1a = *(const float4*)&h32[1][kq * 8];
            float4 h1b = *(const float4*)&h32[1][kq * 8 + 4];
            uint4 wv2 = wp[kq << 10];
            float we0 = u2f(wv2.x << 16), wo0 = u2f(wv2.x & 0xffff0000u);
            float we1 = u2f(wv2.y << 16), wo1 = u2f(wv2.y & 0xffff0000u);
            float we2 = u2f(wv2.z << 16), wo2 = u2f(wv2.z & 0xffff0000u);
            float we3 = u2f(wv2.w << 16), wo3 = u2f(wv2.w & 0xffff0000u);
            a0e = fmaf(h0a.x, we0, a0e); a0o = fmaf(h0a.y, wo0, a0o);
            a1e = fmaf(h1a.x, we0, a1e); a1o = fmaf(h1a.y, wo0, a1o);
            a0e = fmaf(h0a.z, we1, a0e); a0o = fmaf(h0a.w, wo1, a0o);
            a1e = fmaf(h1a.z, we1, a1e); a1o = fmaf(h1a.w, wo1, a1o);
            a0e = fmaf(h0b.x, we2, a0e); a0o = fmaf(h0b.y, wo2, a0o);
            a1e = fmaf(h1b.x, we2, a1e); a1o = fmaf(h1b.y, wo2, a1o);
            a0e = fmaf(h0b.z, we3, a0e); a0o = fmaf(h0b.w, wo3, a0o);
            a1e = fmaf(h1b.z, we3, a1e); a1o = fmaf(h1b.w, wo3, a1o);
        }
        *(float2*)&G2[tid][0] = make_float2(a0e + a0o, a1e + a1o);
        __syncthreads();
        if (tid < 2 * U) {
            float gi = G2[uu][ur], gj = G2[U + uu][ur];
            float gf = G2[2 * U + uu][ur], go = G2[3 * U + uu][ur];
            c_state = c_state * sig_(gf + 1.0f) + sig_(gi) * tanh_(gj);
            h32[ur][uu] = tanh_(c_state) * sig_(go);
        }
        __syncthreads();
    }
    if (tid < 2 * NC) {
        const int r = tid >> 7, n = tid & (NC - 1);
        float sum = bd[n];
        #pragma unroll 4
        for (int k = 0; k < U; ++k)
            sum = fmaf(h32[r][k], Wd[k * NC + n], sum);
        out[(r0 + r) * NC + n] = sum;
    }
}

extern "C" void kernel_launch(void* const* d_in, const int* in_sizes, int n_in,
                              void* d_out, int out_size, void* d_ws, size_t ws_size,
                              hipStream_t stream) {
    const int*   tokens = (const int*)d_in[0];
    const float* Wx     = (const float*)d_in[1];
    const float* Wh     = (const float*)d_in[2];
    const float* bias   = (const float*)d_in[3];
    const float* Wd     = (const float*)d_in[4];
    const float* bd     = (const float*)d_in[5];
    float*       out    = (float*)d_out;

    if (ws_size >= (size_t)WS_NEED) {
        uint4*  Wp  = (uint4*)((char*)d_ws + WP_OFF);
        float4* Wxp = (float4*)((char*)d_ws + WXP_OFF);
        pack_wh<<<128, 256, 0, stream>>>(Wh, Wp);
        pack_wx<<<128, 256, 0, stream>>>(Wx, bias, Wxp);
        lstm_reg<<<512 / BCR, THREADS, 0, stream>>>(tokens, Wp, Wxp, Wd, bd, out);
    } else {
        uint4* Whb = (uint4*)d_ws;
        pack_kq<<<128, 256, 0, stream>>>(Wh, Whb);
        lstm_stream<<<256, 1024, 0, stream>>>(tokens, Wx, Whb, bias, Wd, bd, out);
    }
}

// Round 11
// 4520.132 us; speedup vs baseline: 1.6910x; 1.6910x over previous
//
#include <hip/hip_runtime.h>

// LSTM char-RNN scan: B=512, SEQ=1024, UNITS=256, NUM_CHARS=128. fp32 in/out.
// Round 10: r8 skeleton (best: 5.95 ms) restructured for TLP.
//   Evidence r8/r9/r10: pipe sums ~6-8k cyc/step but measured 14k -> latency-
//   exposure at 2 waves/SIMD is the wall, not issue BW. Changes:
//   - 16 waves (1024 thr, 4/SIMD): per-wave work halves, latency hiding x2.
//   - wave wv owns gates i,j,f,o of unit block wv: nt {wv,16+wv,32+wv,48+wv}
//     = 2 REG nt (64 VGPR) + 1 LDS nt (128 KB total) + 1 STREAM nt
//     (128 KB/step/CU, same as r8).
//   - lo-residual dropped: h is plain bf16 RNE (halves MFMA + A-traffic).
//     Est. absmax ~1e-3 vs 1.758e-3 threshold (W-bf16 alone measured 4.9e-4).
//   - r8's proven 2-barrier step + LDS token window retained.
// Regs (peak): W 64 + acc 16 + wx 16 + misc ~20 = ~116 < 128 cap @ 4 waves/EU.

#define U       256
#define SEQ     1024
#define NC      128
#define GDIM    1024
#define BCR     16         // batch rows per WG
#define THREADS 1024       // 16 waves

typedef short bf16x8 __attribute__((ext_vector_type(8)));
typedef float f32x4  __attribute__((ext_vector_type(4)));

#define WP_OFF   0                        // 512 KB packed W_h
#define WXP_OFF  (512*1024)               // 512 KB packed Wx+bias
#define WS_NEED  (1024*1024)

__device__ __forceinline__ float sig_(float x)  { return 1.0f / (1.0f + __expf(-x)); }
__device__ __forceinline__ float tanh_(float x) { return 1.0f - 2.0f / (__expf(2.0f * x) + 1.0f); }
__device__ __forceinline__ unsigned rne16(float f) {
    union { float f; unsigned u; } v; v.f = f;
    return (v.u + 0x7FFFu + ((v.u >> 16) & 1u)) >> 16;
}
__device__ __forceinline__ float u2f(unsigned u) {
    union { unsigned u; float f; } v; v.u = u; return v.f;
}

// ---- pack W_h into MFMA B-frag order (validated rounds 5-10) ----
// Wp[(nt*8+kt)*64 + lane]: col = nt*16+(lane&15); k = kt*32+(lane>>4)*8 + j,
// dword d packs (k=2d lo, k=2d+1 hi).
__global__ __launch_bounds__(256)
void pack_wh(const float* __restrict__ Wh, uint4* __restrict__ Wp) {
    int i    = blockIdx.x * 256 + threadIdx.x;   // [0, 32768)
    int lane = i & 63;
    int kt   = (i >> 6) & 7;
    int nt   = i >> 9;
    int col  = nt * 16 + (lane & 15);
    int k0   = kt * 32 + ((lane >> 4) * 8);
    const float* base = Wh + (size_t)k0 * GDIM + col;
    unsigned p0 = rne16(base[0 * GDIM]) | (rne16(base[1 * GDIM]) << 16);
    unsigned p1 = rne16(base[2 * GDIM]) | (rne16(base[3 * GDIM]) << 16);
    unsigned p2 = rne16(base[4 * GDIM]) | (rne16(base[5 * GDIM]) << 16);
    unsigned p3 = rne16(base[6 * GDIM]) | (rne16(base[7 * GDIM]) << 16);
    Wp[i] = make_uint4(p0, p1, p2, p3);
}

// ---- pack Wx + bias (+forget_bias) into float4 per (x, unit) ----
__global__ __launch_bounds__(256)
void pack_wx(const float* __restrict__ Wx, const float* __restrict__ bias,
             float4* __restrict__ Wxp) {
    int i = blockIdx.x * 256 + threadIdx.x;      // [0, 32768)
    int x = i >> 8, u = i & 255;
    const float* r = Wx + (size_t)x * GDIM;
    Wxp[i] = make_float4(r[u]       + bias[u],
                         r[256 + u] + bias[256 + u],
                         r[512 + u] + bias[512 + u] + 1.0f,   // forget_bias
                         r[768 + u] + bias[768 + u]);
}

__global__ __launch_bounds__(THREADS, 4)
void lstm_reg16(const int* __restrict__ tokens,
                const uint4* __restrict__ Wp,     // packed W_h (ws)
                const float4* __restrict__ Wxp,   // packed Wx+b (ws)
                const float* __restrict__ Wd,     // [256,128]
                const float* __restrict__ bd,     // [128]
                float* __restrict__ out)          // [512,128]
{
    __shared__ uint4 LW[16][8][64];   // 128 KB  W in LDS (1 nt per wave)
    __shared__ short AH[8][64][8];    // 8 KB    h bf16, MFMA-A swizzled
    __shared__ int   tokw[64][16];    // 4 KB    64-step token window

    const int tid  = threadIdx.x;
    const int wv   = tid >> 6;        // wave 0..15
    const int lane = tid & 63;
    const int m    = lane & 15;
    const int quad = lane >> 4;
    const int r0   = blockIdx.x * BCR;

    // wave wv owns unit block wv (units wv*16+m); gates i,j,f,o at
    // nt = wv, 16+wv, 32+wv, 48+wv.  REG: {wv, 16+wv}. LDS: {32+wv}.
    // STREAM: {48+wv}.
    bf16x8 WR[2][8];                  // 64 VGPRs
    #pragma unroll
    for (int jj = 0; jj < 2; ++jj)
        #pragma unroll
        for (int kt = 0; kt < 8; ++kt) {
            union { uint4 u; bf16x8 v; } c;
            c.u = Wp[((size_t)((wv + 16 * jj) * 8 + kt)) * 64 + lane];
            WR[jj][kt] = c.v;
        }
    #pragma unroll
    for (int kt = 0; kt < 8; ++kt)
        LW[wv][kt][lane] = Wp[((size_t)((32 + wv) * 8 + kt)) * 64 + lane];
    for (int i = tid; i < 2048; i += THREADS)    // zero A plane (as ints)
        ((int*)AH)[i] = 0;

    float cst[4] = {0.f, 0.f, 0.f, 0.f};
    const int uA = wv * 16 + m;
    const int kt_u = uA >> 5, qa = (uA >> 3) & 3, ju = uA & 7;
    const uint4* sp = Wp + ((size_t)(48 + wv) * 8) * 64 + lane;

    __syncthreads();

    for (int t = 0; t < SEQ; ++t) {
        if ((t & 63) == 0) {           // refresh token window
            tokw[tid >> 4][tid & 15] =
                tokens[(size_t)(r0 + (tid & 15)) * SEQ + t + (tid >> 4)];
            __syncthreads();
        }

        // ---- MFMA phase: 4 acc x 8 kt ----
        f32x4 acc[4];
        #pragma unroll
        for (int j = 0; j < 4; ++j) acc[j] = (f32x4){0.f, 0.f, 0.f, 0.f};

        uint4 s = sp[0];
        #pragma unroll
        for (int kt = 0; kt < 8; ++kt) {
            bf16x8 ah = *(const bf16x8*)&AH[kt][lane][0];
            uint4 n;
            if (kt < 7) n = sp[(kt + 1) * 64];
            union { uint4 u; bf16x8 v; } l, b;
            l.u = LW[wv][kt][lane];
            b.u = s;
            acc[0] = __builtin_amdgcn_mfma_f32_16x16x32_bf16(ah, WR[0][kt], acc[0], 0, 0, 0);
            acc[1] = __builtin_amdgcn_mfma_f32_16x16x32_bf16(ah, WR[1][kt], acc[1], 0, 0, 0);
            acc[2] = __builtin_amdgcn_mfma_f32_16x16x32_bf16(ah, l.v, acc[2], 0, 0, 0);
            acc[3] = __builtin_amdgcn_mfma_f32_16x16x32_bf16(ah, b.v, acc[3], 0, 0, 0);
            s = n;
        }

        // ---- in-register LSTM update (4 rows per lane, 1 unit) ----
        unsigned hh[4];
        #pragma unroll
        for (int ri = 0; ri < 4; ++ri) {
            const int x = tokw[t & 63][quad * 4 + ri];
            float4 wx = Wxp[(size_t)x * 256 + uA];
            float gi = acc[0][ri] + wx.x;
            float gj = acc[1][ri] + wx.y;
            float gf = acc[2][ri] + wx.z;    // forget_bias folded
            float go = acc[3][ri] + wx.w;
            float c  = cst[ri];
            c = c * sig_(gf) + sig_(gi) * tanh_(gj);
            cst[ri] = c;
            hh[ri] = rne16(tanh_(c) * sig_(go));
        }
        __syncthreads();       // all A-reads of this step complete

        #pragma unroll
        for (int ri = 0; ri < 4; ++ri)
            AH[kt_u][qa * 16 + quad * 4 + ri][ju] = (short)hh[ri];
        __syncthreads();       // new h visible
    }

    // ---- final dense (h is bf16) ----
    for (int o = tid; o < BCR * NC; o += THREADS) {
        const int r = o >> 7;
        const int n = o & (NC - 1);
        float sum = bd[n];
        #pragma unroll 4
        for (int k = 0; k < U; ++k) {
            float hk = u2f(((unsigned)(unsigned short)
                            AH[k >> 5][((k >> 3) & 3) * 16 + r][k & 7]) << 16);
            sum = fmaf(hk, Wd[k * NC + n], sum);
        }
        out[(size_t)(r0 + r) * NC + n] = sum;
    }
}

// ================= fallback: round-5 streaming kernel (proven 7.6 ms) =========
__global__ __launch_bounds__(256)
void pack_kq(const float* __restrict__ Wh, uint4* __restrict__ Whb) {
    int idx = blockIdx.x * 256 + threadIdx.x;
    int kq  = idx >> 10;
    int c   = idx & 1023;
    const float* base = Wh + (size_t)(kq * 8) * GDIM + c;
    unsigned p0 = rne16(base[0 * GDIM]) | (rne16(base[1 * GDIM]) << 16);
    unsigned p1 = rne16(base[2 * GDIM]) | (rne16(base[3 * GDIM]) << 16);
    unsigned p2 = rne16(base[4 * GDIM]) | (rne16(base[5 * GDIM]) << 16);
    unsigned p3 = rne16(base[6 * GDIM]) | (rne16(base[7 * GDIM]) << 16);
    Whb[idx] = make_uint4(p0, p1, p2, p3);
}

__global__ __launch_bounds__(1024, 4)
void lstm_stream(const int* __restrict__ tokens, const float* __restrict__ Wx,
                 const uint4* __restrict__ Whb, const float* __restrict__ bias,
                 const float* __restrict__ Wd, const float* __restrict__ bd,
                 float* __restrict__ out)
{
    __shared__ float h32[2][U];
    __shared__ float G2[GDIM][2];
    __shared__ int   tok[2][SEQ];
    const int tid = threadIdx.x;
    const int r0  = blockIdx.x * 2;
    for (int i = tid; i < 2 * SEQ; i += 1024)
        ((int*)tok)[i] = tokens[r0 * SEQ + i];
    if (tid < 2 * U) ((float*)h32)[tid] = 0.0f;
    const float b_c = bias[tid];
    float c_state = 0.0f;
    const int ur = tid >> 8, uu = tid & 255;
    __syncthreads();
    const uint4* wp = Whb + tid;
    for (int t = 0; t < SEQ; ++t) {
        const int x0 = tok[0][t], x1 = tok[1][t];
        float a0e = Wx[x0 * GDIM + tid] + b_c;
        float a1e = Wx[x1 * GDIM + tid] + b_c;
        float a0o = 0.f, a1o = 0.f;
        #pragma unroll 4
        for (int kq = 0; kq < 32; ++kq) {
            float4 h0a = *(const float4*)&h32[0][kq * 8];
            float4 h0b = *(const float4*)&h32[0][kq * 8 + 4];
            float4 h1a = *(const float4*)&h32[1][kq * 8];
            float4 h1b = *(const float4*)&h32[1][kq * 8 + 4];
            uint4 wv2 = wp[kq << 10];
            float we0 = u2f(wv2.x << 16), wo0 = u2f(wv2.x & 0xffff0000u);
            float we1 = u2f(wv2.y << 16), wo1 = u2f(wv2.y & 0xffff0000u);
            float we2 = u2f(wv2.z << 16), wo2 = u2f(wv2.z & 0xffff0000u);
            float we3 = u2f(wv2.w << 16), wo3 = u2f(wv2.w & 0xffff0000u);
            a0e = fmaf(h0a.x, we0, a0e); a0o = fmaf(h0a.y, wo0, a0o);
            a1e = fmaf(h1a.x, we0, a1e); a1o = fmaf(h1a.y, wo0, a1o);
            a0e = fmaf(h0a.z, we1, a0e); a0o = fmaf(h0a.w, wo1, a0o);
            a1e = fmaf(h1a.z, we1, a1e); a1o = fmaf(h1a.w, wo1, a1o);
            a0e = fmaf(h0b.x, we2, a0e); a0o = fmaf(h0b.y, wo2, a0o);
            a1e = fmaf(h1b.x, we2, a1e); a1o = fmaf(h1b.y, wo2, a1o);
            a0e = fmaf(h0b.z, we3, a0e); a0o = fmaf(h0b.w, wo3, a0o);
            a1e = fmaf(h1b.z, we3, a1e); a1o = fmaf(h1b.w, wo3, a1o);
        }
        *(float2*)&G2[tid][0] = make_float2(a0e + a0o, a1e + a1o);
        __syncthreads();
        if (tid < 2 * U) {
            float gi = G2[uu][ur], gj = G2[U + uu][ur];
            float gf = G2[2 * U + uu][ur], go = G2[3 * U + uu][ur];
            c_state = c_state * sig_(gf + 1.0f) + sig_(gi) * tanh_(gj);
            h32[ur][uu] = tanh_(c_state) * sig_(go);
        }
        __syncthreads();
    }
    if (tid < 2 * NC) {
        const int r = tid >> 7, n = tid & (NC - 1);
        float sum = bd[n];
        #pragma unroll 4
        for (int k = 0; k < U; ++k)
            sum = fmaf(h32[r][k], Wd[k * NC + n], sum);
        out[(r0 + r) * NC + n] = sum;
    }
}

extern "C" void kernel_launch(void* const* d_in, const int* in_sizes, int n_in,
                              void* d_out, int out_size, void* d_ws, size_t ws_size,
                              hipStream_t stream) {
    const int*   tokens = (const int*)d_in[0];
    const float* Wx     = (const float*)d_in[1];
    const float* Wh     = (const float*)d_in[2];
    const float* bias   = (const float*)d_in[3];
    const float* Wd     = (const float*)d_in[4];
    const float* bd     = (const float*)d_in[5];
    float*       out    = (float*)d_out;

    if (ws_size >= (size_t)WS_NEED) {
        uint4*  Wp  = (uint4*)((char*)d_ws + WP_OFF);
        float4* Wxp = (float4*)((char*)d_ws + WXP_OFF);
        pack_wh<<<128, 256, 0, stream>>>(Wh, Wp);
        pack_wx<<<128, 256, 0, stream>>>(Wx, bias, Wxp);
        lstm_reg16<<<512 / BCR, THREADS, 0, stream>>>(tokens, Wp, Wxp, Wd, bd, out);
    } else {
        uint4* Whb = (uint4*)d_ws;
        pack_kq<<<128, 256, 0, stream>>>(Wh, Whb);
        lstm_stream<<<256, 1024, 0, stream>>>(tokens, Wx, Whb, bias, Wd, bd, out);
    }
}